// Round 7
// baseline (103.461 us; speedup 1.0000x reference)
//
#include <hip/hip_runtime.h>
#include <hip/hip_bf16.h>
#include <math.h>

// Problem constants
#define B_     2
#define CIN    32
#define HH     512
#define WW     512
#define HID    768
#define SZ     16
#define NPATCH 1024      // 32x32 patch grid
#define KDIM   8192      // CIN*SZ*SZ
#define NCLS   21
#define LAT    128
#define LC     2688      // LAT*NCLS
#define NP     (B_ * NPATCH)   // 2048 patch rows

// prep-kernel block ranges (classlat FIRST so it overlaps the bulk)
#define NB_CL  63        // NCLS*3 : classlat (cls, 256-wide d-segment), norms inline
#define NB_W4  1536      // HID*KDIM/16/256  (4 float4 per thread)

typedef __attribute__((ext_vector_type(8))) short short8;   // 8 bf16 (4 VGPR)
typedef __attribute__((ext_vector_type(4))) float f32x4;

// RNE float->bf16
__device__ __forceinline__ ushort f2bf(float f) {
    union { float f; unsigned u; } v; v.f = f;
    unsigned r = (v.u + 0x7fff + ((v.u >> 16) & 1)) >> 16;
    return (ushort)r;
}
__device__ __forceinline__ float bf2f(ushort u) {
    union { unsigned u; float f; } v; v.u = (unsigned)u << 16;
    return v.f;
}

__device__ __forceinline__ void gload16(const void* g, void* l) {
    __builtin_amdgcn_global_load_lds(
        (const __attribute__((address_space(1))) unsigned int*)g,
        (__attribute__((address_space(3))) unsigned int*)l, 16, 0, 0);
}

// pack 2 f32 -> 1 u32 of 2 bf16 (RNE) via HIP intrinsic (compiles to v_cvt_pk)
__device__ __forceinline__ unsigned pk2bf(float a, float b) {
    union { __hip_bfloat162 h; unsigned u; } cv;
    cv.h = __float22bfloat162_rn(make_float2(a, b));
    return cv.u;
}

// ---------------------------------------------------------------------------
// Fused prep kernel.  ROUND-7: the x->bf16 transpose branch is GONE — the
// GEMM now converts x in-staging (4 prep variants all pinned at ~40-52us;
// killing the xb round-trip saves ~67MB HBM + 2048 blocks).
//   blocks [0, NB_CL)    : classlat (norms inline, 3 d-segments per class)
//   blocks [.., +NB_W4)  : conv_w f32 -> bf16 (4-deep batch, dense both sides)
// ---------------------------------------------------------------------------
__global__ __launch_bounds__(256) void k_prep(const float* __restrict__ w,
                                              const float* __restrict__ lat,
                                              ushort* __restrict__ wb,
                                              float* __restrict__ classlat) {
    const int bid = blockIdx.x;
    const int t   = threadIdx.x;

    if (bid < NB_CL) {
        // ---- classlat with inline row norms ----
        const int cls  = bid / 3;
        const int dseg = bid % 3;
        const int lane = t & 63, wvv = t >> 6;
        __shared__ float sc_sh[LAT];

        for (int q = 0; q < 32; q += 2) {
            int u0 = wvv * 32 + q;
            const float* r0 = lat + (size_t)(u0 * NCLS + cls) * HID;
            const float* r1 = lat + (size_t)((u0 + 1) * NCLS + cls) * HID;
            float s0 = 0.f, s1 = 0.f;
#pragma unroll
            for (int e = 0; e < HID / 64; ++e) {
                float a = r0[lane + e * 64]; s0 += a * a;
                float b2 = r1[lane + e * 64]; s1 += b2 * b2;
            }
#pragma unroll
            for (int off = 32; off >= 1; off >>= 1) {
                s0 += __shfl_xor(s0, off, 64);
                s1 += __shfl_xor(s1, off, 64);
            }
            if (lane == 0) {
                sc_sh[u0]     = 1.0f / (128.0f * sqrtf(s0));
                sc_sh[u0 + 1] = 1.0f / (128.0f * sqrtf(s1));
            }
        }
        __syncthreads();

        const float* src = lat + (size_t)cls * HID + dseg * 256 + t;
        float a = 0.f;
        for (int u0 = 0; u0 < LAT; u0 += 8) {
            float v[8];
#pragma unroll
            for (int q = 0; q < 8; ++q)
                v[q] = src[(size_t)(u0 + q) * (NCLS * HID)];
#pragma unroll
            for (int q = 0; q < 8; ++q) a += v[q] * sc_sh[u0 + q];
        }
        classlat[cls * HID + dseg * 256 + t] = a;
    } else {
        // ---- conv_w convert (coalesced both sides, 4 loads in flight) ----
        const int cb = bid - NB_CL;
        float4 vv[4];
#pragma unroll
        for (int k = 0; k < 4; ++k)
            vv[k] = *(const float4*)(w + ((size_t)cb * 1024 + k * 256 + t) * 4);
#pragma unroll
        for (int k = 0; k < 4; ++k) {
            ushort4 o;
            o.x = f2bf(vv[k].x); o.y = f2bf(vv[k].y);
            o.z = f2bf(vv[k].z); o.w = f2bf(vv[k].w);
            *(ushort4*)(wb + ((size_t)cb * 1024 + k * 256 + t) * 4) = o;
        }
    }
}

// ---------------------------------------------------------------------------
// MFMA GEMM with FUSED x->bf16 convert in A-staging.
// patch[p][d] = sum_k x-as-A[p][k] * wb[d][k],  k = c*256 + i*16 + j.
// 256x128 tile, BK=64, 8 waves (4x2), wave-level 4x4 mfma_f32_16x16x32_bf16.
// A: an A-tile's 64-k slice = 32 contiguous 2KB rows of x (f32).  Reg-staged:
//    global_load_dwordx4 -> cvt_pk bf16 -> ds_write_b64 into Als[256][72]
//    (row pad 144B: staging b64 writes land 4 dwords/bank = conflict-free;
//    ds_read_b128 at stride-36-dwords is uniform 8/bank = minimum).  No XOR.
// B: unchanged verified path — gload16 + T2 XOR swizzle (rule #21).
// T1 bijective XCD remap: each XCD owns one split-K slice; slice bz covers
// c in [bz*4, bz*4+4) so x is HBM-read once; panel re-reads hit per-XCD L2.
// Output layout: pbuf[p][z][d]
// ---------------------------------------------------------------------------
template <int SPLITK>
__global__ __launch_bounds__(512) void k_gemm(const float* __restrict__ x,
                                              const ushort* __restrict__ wb,
                                              ushort* __restrict__ pbuf) {
    constexpr int KS = KDIM / SPLITK;
    __shared__ ushort Als[256 * 72];   // [row][64+8 pad] 36,864 B
    __shared__ ushort Bls[128 * 64];   // 16,384 B

    // ---- T1 remap: grid (8, 6, SPLITK), nwg = 48*SPLITK (always %8==0) ----
    const int flat = blockIdx.x + 8 * (blockIdx.y + 6 * blockIdx.z);
    constexpr int nwg = 48 * SPLITK;
    const int wg = (flat & 7) * (nwg >> 3) + (flat >> 3);
    const int bz = wg / 48;
    const int rr = wg - bz * 48;
    const int by = rr % 6;       // by-fastest: consecutive blocks share the A panel
    const int bx = rr / 6;

    const int tid  = threadIdx.x;
    const int wv   = tid >> 6;         // 0..7
    const int lane = tid & 63;
    const int wm   = (wv >> 1) * 64;   // wave row offset in tile (0..192)
    const int wn   = (wv & 1) * 64;    // wave col offset in tile (0/64)

    const int bxb = bx >> 2;           // batch index
    const int ph0 = (bx & 3) * 8;      // first ph of this tile

    const size_t bbase = ((size_t)by * 128) * KDIM + (size_t)bz * KS;

    const int srow  = wv * 8 + (lane >> 3);                    // + q*64 (B rows)
    const int skoff = (((lane & 7) ^ (lane >> 3)) * 8);        // B swizzled source elem

    f32x4 acc[4][4];
#pragma unroll
    for (int m = 0; m < 4; ++m)
#pragma unroll
        for (int n = 0; n < 4; ++n) acc[m][n] = (f32x4)(0.f);

    const int fr = lane & 15, fq = lane >> 4;
    const int frx = (fr & 7) * 8;   // B read-side XOR (elements)

    for (int kk = 0; kk < KS; kk += 64) {
        const int gk = bz * KS + kk;            // global k, multiple of 64
        const int c  = gk >> 8;                 // input channel
        const int i0 = (gk >> 4) & 15;          // 0,4,8,12
        const float* xA = x + (((size_t)(bxb * CIN + c) * HH) + ph0 * 16 + i0) * WW;

        // ---- A staging: 32 x-rows x 512 f32 = 4096 float4, 8 per thread ----
        float4 vv[8];
#pragma unroll
        for (int q = 0; q < 8; ++q) {
            int f    = q * 512 + tid;           // 0..4095
            int row5 = f >> 7;                  // 0..31 : (ph_rel<<2)|i_rel
            int w4   = f & 127;
            vv[q] = *(const float4*)(xA + (size_t)((row5 >> 2) * 16 + (row5 & 3)) * WW
                                        + w4 * 4);
        }
        // ---- B staging (async direct-to-LDS, verified path) ----
#pragma unroll
        for (int q = 0; q < 2; ++q) {
            const int row = q * 64 + srow;
            gload16(&wb[bbase + (size_t)row * KDIM + kk + skoff],
                    &Bls[(q * 64 + wv * 8) * 64]);
        }
        // ---- A convert + LDS write (conflict-free per bank analysis) ----
#pragma unroll
        for (int q = 0; q < 8; ++q) {
            int f    = q * 512 + tid;
            int row5 = f >> 7;
            int w4   = f & 127;
            int r    = ((row5 >> 2) << 5) + (w4 >> 2);      // tile row 0..255
            int e    = ((row5 & 3) << 4) + ((w4 & 3) << 2); // k-elem 0..60
            uint2 o;
            o.x = pk2bf(vv[q].x, vv[q].y);
            o.y = pk2bf(vv[q].z, vv[q].w);
            *(uint2*)&Als[r * 72 + e] = o;
        }
        __syncthreads();   // drains lgkm (A writes) + vmcnt (B gload_lds)

#pragma unroll
        for (int s = 0; s < 2; ++s) {
            short8 af[4], bf[4];
#pragma unroll
            for (int m = 0; m < 4; ++m)
                af[m] = *(const short8*)&Als[(wm + m * 16 + fr) * 72 + s * 32 + fq * 8];
#pragma unroll
            for (int n = 0; n < 4; ++n)
                bf[n] = *(const short8*)&Bls[(wn + n * 16 + fr) * 64 + ((s * 32 + fq * 8) ^ frx)];
#pragma unroll
            for (int m = 0; m < 4; ++m)
#pragma unroll
                for (int n = 0; n < 4; ++n)
                    acc[m][n] = __builtin_amdgcn_mfma_f32_16x16x32_bf16(af[m], bf[n], acc[m][n], 0, 0, 0);
        }
        __syncthreads();
    }

#pragma unroll
    for (int m = 0; m < 4; ++m) {
#pragma unroll
        for (int n = 0; n < 4; ++n) {
            int col = by * 128 + wn + n * 16 + fr;
#pragma unroll
            for (int j = 0; j < 4; ++j) {
                int row = bx * 256 + wm + m * 16 + fq * 4 + j;
                pbuf[((size_t)row * SPLITK + bz) * HID + col] = f2bf(acc[m][n][j]);
            }
        }
    }
}

// ---------------------------------------------------------------------------
// Per-patch epilogue: stage the patch's contiguous [SPLITK][HID] bf16 partials
// into LDS (coalesced 16B loads), sum + bias -> norm -> 21 dots ->
// masked exp(2*sim) -> partial[p].  (Global reduce stays a separate tiny
// kernel: 2048 same-address device atomics cost ~40us — measured round 1.)
// ---------------------------------------------------------------------------
template <int SPLITK>
__global__ __launch_bounds__(256) void k_final(const ushort* __restrict__ pbuf,
                                               const float* __restrict__ conv_b,
                                               const float* __restrict__ classlat,
                                               const int* __restrict__ mask,
                                               float* __restrict__ partial) {
    const int p = blockIdx.x;        // 0..2047
    const int b = p >> 10, n = p & 1023;
    const int t = threadIdx.x;
    const int lane = t & 63, wv = t >> 6;

    __shared__ ushort sh[SPLITK * HID];
    const ushort* pb = pbuf + (size_t)p * (SPLITK * HID);
    for (int i = t; i < SPLITK * HID / 8; i += 256)
        *(short8*)&sh[i * 8] = *(const short8*)&pb[(size_t)i * 8];
    __syncthreads();

    float f0 = conv_b[t], f1 = conv_b[t + 256], f2 = conv_b[t + 512];
#pragma unroll
    for (int z = 0; z < SPLITK; ++z) {
        f0 += bf2f(sh[z * HID + t]);
        f1 += bf2f(sh[z * HID + t + 256]);
        f2 += bf2f(sh[z * HID + t + 512]);
    }

    __shared__ float wsum[4];
    __shared__ float wdot[4][NCLS];
    __shared__ float cpart[NCLS];

    float ss = f0 * f0 + f1 * f1 + f2 * f2;
#pragma unroll
    for (int off = 32; off >= 1; off >>= 1) ss += __shfl_xor(ss, off, 64);
    if (lane == 0) wsum[wv] = ss;

    float dots[NCLS];
#pragma unroll
    for (int c = 0; c < NCLS; ++c) {
        const float* cl = classlat + c * HID;
        dots[c] = cl[t] * f0 + cl[t + 256] * f1 + cl[t + 512] * f2;
    }
#pragma unroll
    for (int c = 0; c < NCLS; ++c) {
        float v = dots[c];
#pragma unroll
        for (int off = 32; off >= 1; off >>= 1) v += __shfl_xor(v, off, 64);
        if (lane == 0) wdot[wv][c] = v;
    }
    __syncthreads();

    if (t < NCLS) {
        float tot  = wsum[0] + wsum[1] + wsum[2] + wsum[3];
        float invn = 1.0f / sqrtf(tot);
        float dot  = wdot[0][t] + wdot[1][t] + wdot[2][t] + wdot[3][t];
        float sim  = dot * invn;
        int   mv   = mask[(size_t)(b * NCLS + t) * NPATCH + n];
        cpart[t]   = (mv != 0) ? expf(sim * 2.0f) : 0.0f;
    }
    __syncthreads();
    if (t == 0) {
        float s = 0.f;
#pragma unroll
        for (int c = 0; c < NCLS; ++c) s += cpart[c];
        partial[p] = s;
    }
}

__global__ __launch_bounds__(256) void k_reduce(const float* __restrict__ partial,
                                                float* __restrict__ out) {
    int t = threadIdx.x;
    float s = 0.f;
    for (int i = t; i < NP; i += 256) s += partial[i];
#pragma unroll
    for (int off = 32; off >= 1; off >>= 1) s += __shfl_xor(s, off, 64);
    __shared__ float ws[4];
    if ((t & 63) == 0) ws[t >> 6] = s;
    __syncthreads();
    if (t == 0) out[0] = -logf(ws[0] + ws[1] + ws[2] + ws[3]);
}

// ---------------------------------------------------------------------------
extern "C" void kernel_launch(void* const* d_in, const int* in_sizes, int n_in,
                              void* d_out, int out_size, void* d_ws, size_t ws_size,
                              hipStream_t stream) {
    const float* x      = (const float*)d_in[0];
    const int*   mask   = (const int*)d_in[1];
    const float* conv_w = (const float*)d_in[2];
    const float* conv_b = (const float*)d_in[3];
    const float* latent = (const float*)d_in[4];
    float* out = (float*)d_out;

    // workspace layout (bytes) — xb is GONE (fused into k_gemm)
    const size_t wb_bytes   = (size_t)HID * KDIM * 2;       // 12,582,912
    const size_t pslice     = (size_t)NP * HID * 2;         // 3,145,728 (bf16)
    const size_t small_need = (size_t)NCLS * HID * 4 + NP * 4 + 256;

    char* base = (char*)d_ws;
    ushort* wb   = (ushort*)base;
    ushort* pbuf = (ushort*)(base + wb_bytes);

    int splitk = 1;
    const size_t fixed = wb_bytes + small_need;
    if (ws_size >= fixed + 8 * pslice)      splitk = 8;
    else if (ws_size >= fixed + 4 * pslice) splitk = 4;
    else if (ws_size >= fixed + 2 * pslice) splitk = 2;

    float* classlat = (float*)(base + wb_bytes + (size_t)splitk * pslice);
    float* partial  = classlat + NCLS * HID;

    k_prep<<<NB_CL + NB_W4, 256, 0, stream>>>(conv_w, latent, wb, classlat);

    dim3 g(NP / 256, HID / 128, splitk);
    switch (splitk) {
        case 8: k_gemm<8><<<g, 512, 0, stream>>>(x, wb, pbuf); break;
        case 4: k_gemm<4><<<g, 512, 0, stream>>>(x, wb, pbuf); break;
        case 2: k_gemm<2><<<g, 512, 0, stream>>>(x, wb, pbuf); break;
        default: k_gemm<1><<<g, 512, 0, stream>>>(x, wb, pbuf); break;
    }

    switch (splitk) {
        case 8: k_final<8><<<NP, 256, 0, stream>>>(pbuf, conv_b, classlat, mask, partial); break;
        case 4: k_final<4><<<NP, 256, 0, stream>>>(pbuf, conv_b, classlat, mask, partial); break;
        case 2: k_final<2><<<NP, 256, 0, stream>>>(pbuf, conv_b, classlat, mask, partial); break;
        default: k_final<1><<<NP, 256, 0, stream>>>(pbuf, conv_b, classlat, mask, partial); break;
    }
    k_reduce<<<1, 256, 0, stream>>>(partial, out);
}

// Round 8
// 86.548 us; speedup vs baseline: 1.1954x; 1.1954x over previous
//
#include <hip/hip_runtime.h>
#include <hip/hip_bf16.h>
#include <math.h>

// Problem constants
#define B_     2
#define CIN    32
#define HH     512
#define WW     512
#define HID    768
#define SZ     16
#define NPATCH 1024      // 32x32 patch grid
#define KDIM   8192      // CIN*SZ*SZ
#define NCLS   21
#define LAT    128
#define LC     2688      // LAT*NCLS
#define NP     (B_ * NPATCH)   // 2048 patch rows

// prep-kernel block ranges (classlat FIRST: longest serial chain)
#define NB_CL  63        // NCLS*3 : classlat (cls, 256-wide d-segment), norms inline
#define NB_W4  1536      // HID*KDIM/16/256  (4 float4 per thread)
#define NB_XC  4096      // x f32 -> bf16 pass-through copy, 16 elems/thread

typedef __attribute__((ext_vector_type(8))) short short8;   // 8 bf16 (4 VGPR)
typedef __attribute__((ext_vector_type(4))) float f32x4;

// RNE float->bf16
__device__ __forceinline__ ushort f2bf(float f) {
    union { float f; unsigned u; } v; v.f = f;
    unsigned r = (v.u + 0x7fff + ((v.u >> 16) & 1)) >> 16;
    return (ushort)r;
}
__device__ __forceinline__ float bf2f(ushort u) {
    union { unsigned u; float f; } v; v.u = (unsigned)u << 16;
    return v.f;
}

__device__ __forceinline__ void gload16(const void* g, void* l) {
    __builtin_amdgcn_global_load_lds(
        (const __attribute__((address_space(1))) unsigned int*)g,
        (__attribute__((address_space(3))) unsigned int*)l, 16, 0, 0);
}

// ---------------------------------------------------------------------------
// Fused prep kernel.  ROUND-8: NO transpose anywhere.  x is pass-through
// converted to row-major bf16 (xbf, same layout as x) — a pure streaming
// copy at fillBuffer-class BW.  The GEMM gathers its transposed A-tile via
// per-lane gload16 source addresses (m104/m173: global src IS per-lane).
//   blocks [0, NB_CL)    : classlat (norms inline, 3 d-segments per class)
//   blocks [.., +NB_W4)  : conv_w f32 -> bf16 (4-deep batch, dense both sides)
//   blocks [.., +NB_XC)  : x f32 -> bf16 copy (16 elems/thread, all dense)
// ---------------------------------------------------------------------------
__global__ __launch_bounds__(256) void k_prep(const float* __restrict__ w,
                                              const float* __restrict__ x,
                                              const float* __restrict__ lat,
                                              ushort* __restrict__ wb,
                                              ushort* __restrict__ xbf,
                                              float* __restrict__ classlat) {
    const int bid = blockIdx.x;
    const int t   = threadIdx.x;

    if (bid < NB_CL) {
        // ---- classlat with inline row norms ----
        const int cls  = bid / 3;
        const int dseg = bid % 3;
        const int lane = t & 63, wvv = t >> 6;
        __shared__ float sc_sh[LAT];

        for (int q = 0; q < 32; q += 2) {
            int u0 = wvv * 32 + q;
            const float* r0 = lat + (size_t)(u0 * NCLS + cls) * HID;
            const float* r1 = lat + (size_t)((u0 + 1) * NCLS + cls) * HID;
            float s0 = 0.f, s1 = 0.f;
#pragma unroll
            for (int e = 0; e < HID / 64; ++e) {
                float a = r0[lane + e * 64]; s0 += a * a;
                float b2 = r1[lane + e * 64]; s1 += b2 * b2;
            }
#pragma unroll
            for (int off = 32; off >= 1; off >>= 1) {
                s0 += __shfl_xor(s0, off, 64);
                s1 += __shfl_xor(s1, off, 64);
            }
            if (lane == 0) {
                sc_sh[u0]     = 1.0f / (128.0f * sqrtf(s0));
                sc_sh[u0 + 1] = 1.0f / (128.0f * sqrtf(s1));
            }
        }
        __syncthreads();

        const float* src = lat + (size_t)cls * HID + dseg * 256 + t;
        float a = 0.f;
        for (int u0 = 0; u0 < LAT; u0 += 8) {
            float v[8];
#pragma unroll
            for (int q = 0; q < 8; ++q)
                v[q] = src[(size_t)(u0 + q) * (NCLS * HID)];
#pragma unroll
            for (int q = 0; q < 8; ++q) a += v[q] * sc_sh[u0 + q];
        }
        classlat[cls * HID + dseg * 256 + t] = a;
    } else if (bid < NB_CL + NB_W4) {
        // ---- conv_w convert (coalesced both sides, 4 loads in flight) ----
        const int cb = bid - NB_CL;
        float4 vv[4];
#pragma unroll
        for (int k = 0; k < 4; ++k)
            vv[k] = *(const float4*)(w + ((size_t)cb * 1024 + k * 256 + t) * 4);
#pragma unroll
        for (int k = 0; k < 4; ++k) {
            ushort4 o;
            o.x = f2bf(vv[k].x); o.y = f2bf(vv[k].y);
            o.z = f2bf(vv[k].z); o.w = f2bf(vv[k].w);
            *(ushort4*)(wb + ((size_t)cb * 1024 + k * 256 + t) * 4) = o;
        }
    } else {
        // ---- x f32 -> bf16 pass-through copy (fully dense both sides) ----
        const size_t e0 = ((size_t)(bid - NB_CL - NB_W4) * 256 + t) * 16;
        float4 vv[4];
#pragma unroll
        for (int k = 0; k < 4; ++k)
            vv[k] = *(const float4*)(x + e0 + k * 4);
        ushort o[16];
#pragma unroll
        for (int k = 0; k < 4; ++k) {
            o[k * 4 + 0] = f2bf(vv[k].x); o[k * 4 + 1] = f2bf(vv[k].y);
            o[k * 4 + 2] = f2bf(vv[k].z); o[k * 4 + 3] = f2bf(vv[k].w);
        }
        *(short8*)&xbf[e0]     = *(short8*)&o[0];
        *(short8*)&xbf[e0 + 8] = *(short8*)&o[8];
    }
}

// ---------------------------------------------------------------------------
// MFMA GEMM reading A straight from row-major bf16 xbf via per-lane gload16
// gather (the "transpose" lives in the address computation; LDS content,
// XOR swizzle, read path, MFMA and epilogue are bit-identical to round 6).
// patch[p][d] = sum_k xbf-as-A[p][k] * wb[d][k],  k = c*256 + i*16 + j.
// 256x128 tile, BK=64, 8 waves (4x2), wave 64x64 via 4x4 mfma 16x16x32 bf16.
// A: LDS chunk n=r*8+e (16B) <- xbf elements (c, i0+(e_src>>1),
//    pw*16+(e_src&1)*8) with e_src = e ^ (r&7)  [T2 swizzle via source addr,
//    rule #21].  Per-lane offset is ITER-INVARIANT; per K-step adds only
//    wave-uniform c*262144 + i0*512.  Each wave-issue = 4 x 256B segments.
// B: unchanged verified path — gload16 + XOR swizzle.
// T1 bijective XCD remap: each XCD owns one split-K slice (c in [bz*4,bz*4+4)).
// Output layout: pbuf[p][z][d]
// ---------------------------------------------------------------------------
template <int SPLITK>
__global__ __launch_bounds__(512) void k_gemm(const ushort* __restrict__ xbf,
                                              const ushort* __restrict__ wb,
                                              ushort* __restrict__ pbuf) {
    constexpr int KS = KDIM / SPLITK;
    __shared__ ushort Als[256 * 64];   // [row][k] 32 KB (content == round 6)
    __shared__ ushort Bls[128 * 64];   // 16 KB

    // ---- T1 remap: grid (8, 6, SPLITK), nwg = 48*SPLITK (always %8==0) ----
    const int flat = blockIdx.x + 8 * (blockIdx.y + 6 * blockIdx.z);
    constexpr int nwg = 48 * SPLITK;
    const int wg = (flat & 7) * (nwg >> 3) + (flat >> 3);
    const int bz = wg / 48;
    const int rr = wg - bz * 48;
    const int by = rr % 6;       // by-fastest: consecutive blocks share the A panel
    const int bx = rr / 6;

    const int tid  = threadIdx.x;
    const int wv   = tid >> 6;         // 0..7
    const int lane = tid & 63;
    const int wm   = (wv >> 1) * 64;   // wave row offset in tile (0..192)
    const int wn   = (wv & 1) * 64;    // wave col offset in tile (0/64)

    const int bxb = bx >> 2;           // batch index
    const int ph0 = (bx & 3) * 8;      // first ph of this tile

    const size_t bbase = ((size_t)by * 128) * KDIM + (size_t)bz * KS;

    const int srow  = wv * 8 + (lane >> 3);                    // B rows (+ q*64)
    const int skoff = (((lane & 7) ^ (lane >> 3)) * 8);        // B swizzled src elem

    // ---- A gather per-lane invariant offset (ushort elems) ----
    const int hi    = tid >> 8;                       // 0/1
    const int pw    = (tid >> 3) & 31;
    const int esrc  = (tid & 7) ^ ((tid >> 3) & 7);   // T2 swizzle in source
    const size_t laneoff = (size_t)hi * 8192 + (size_t)(esrc >> 1) * 512
                         + pw * 16 + (esrc & 1) * 8;
    // block-uniform base: (b*32)*262144 + ph0*8192
    const size_t xbase0 = (size_t)bxb * 32 * 262144 + (size_t)ph0 * 8192;

    f32x4 acc[4][4];
#pragma unroll
    for (int m = 0; m < 4; ++m)
#pragma unroll
        for (int n = 0; n < 4; ++n) acc[m][n] = (f32x4)(0.f);

    const int fr = lane & 15, fq = lane >> 4;
    const int frx = (fr & 7) * 8;   // read-side XOR (elements), A and B

    for (int kk = 0; kk < KS; kk += 64) {
        const int gk = bz * KS + kk;            // global k, multiple of 64
        const int c  = gk >> 8;                 // input channel
        const int i0 = (gk >> 4) & 15;          // 0,4,8,12
        const ushort* xA = xbf + xbase0 + (size_t)c * 262144 + (size_t)i0 * 512
                         + laneoff;

        // ---- A staging: 2048 chunks, 4 per thread (wave: 4 x 256B segs) ----
#pragma unroll
        for (int q = 0; q < 4; ++q)
            gload16(xA + (size_t)q * 16384, &Als[q * 4096 + wv * 512]);
        // ---- B staging (verified path) ----
#pragma unroll
        for (int q = 0; q < 2; ++q) {
            const int row = q * 64 + srow;
            gload16(&wb[bbase + (size_t)row * KDIM + kk + skoff],
                    &Bls[(q * 64 + wv * 8) * 64]);
        }
        __syncthreads();   // drains vmcnt: tiles ready

#pragma unroll
        for (int s = 0; s < 2; ++s) {
            short8 af[4], bf[4];
#pragma unroll
            for (int m = 0; m < 4; ++m)
                af[m] = *(const short8*)&Als[(wm + m * 16 + fr) * 64 + ((s * 32 + fq * 8) ^ frx)];
#pragma unroll
            for (int n = 0; n < 4; ++n)
                bf[n] = *(const short8*)&Bls[(wn + n * 16 + fr) * 64 + ((s * 32 + fq * 8) ^ frx)];
#pragma unroll
            for (int m = 0; m < 4; ++m)
#pragma unroll
                for (int n = 0; n < 4; ++n)
                    acc[m][n] = __builtin_amdgcn_mfma_f32_16x16x32_bf16(af[m], bf[n], acc[m][n], 0, 0, 0);
        }
        __syncthreads();
    }

#pragma unroll
    for (int m = 0; m < 4; ++m) {
#pragma unroll
        for (int n = 0; n < 4; ++n) {
            int col = by * 128 + wn + n * 16 + fr;
#pragma unroll
            for (int j = 0; j < 4; ++j) {
                int row = bx * 256 + wm + m * 16 + fq * 4 + j;
                pbuf[((size_t)row * SPLITK + bz) * HID + col] = f2bf(acc[m][n][j]);
            }
        }
    }
}

// ---------------------------------------------------------------------------
// Per-patch epilogue: stage the patch's contiguous [SPLITK][HID] bf16 partials
// into LDS (coalesced 16B loads), sum + bias -> norm -> 21 dots ->
// masked exp(2*sim) -> partial[p].  (Global reduce stays a separate tiny
// kernel: 2048 same-address device atomics cost ~40us — measured round 1.)
// ---------------------------------------------------------------------------
template <int SPLITK>
__global__ __launch_bounds__(256) void k_final(const ushort* __restrict__ pbuf,
                                               const float* __restrict__ conv_b,
                                               const float* __restrict__ classlat,
                                               const int* __restrict__ mask,
                                               float* __restrict__ partial) {
    const int p = blockIdx.x;        // 0..2047
    const int b = p >> 10, n = p & 1023;
    const int t = threadIdx.x;
    const int lane = t & 63, wv = t >> 6;

    __shared__ ushort sh[SPLITK * HID];
    const ushort* pb = pbuf + (size_t)p * (SPLITK * HID);
    for (int i = t; i < SPLITK * HID / 8; i += 256)
        *(short8*)&sh[i * 8] = *(const short8*)&pb[(size_t)i * 8];
    __syncthreads();

    float f0 = conv_b[t], f1 = conv_b[t + 256], f2 = conv_b[t + 512];
#pragma unroll
    for (int z = 0; z < SPLITK; ++z) {
        f0 += bf2f(sh[z * HID + t]);
        f1 += bf2f(sh[z * HID + t + 256]);
        f2 += bf2f(sh[z * HID + t + 512]);
    }

    __shared__ float wsum[4];
    __shared__ float wdot[4][NCLS];
    __shared__ float cpart[NCLS];

    float ss = f0 * f0 + f1 * f1 + f2 * f2;
#pragma unroll
    for (int off = 32; off >= 1; off >>= 1) ss += __shfl_xor(ss, off, 64);
    if (lane == 0) wsum[wv] = ss;

    float dots[NCLS];
#pragma unroll
    for (int c = 0; c < NCLS; ++c) {
        const float* cl = classlat + c * HID;
        dots[c] = cl[t] * f0 + cl[t + 256] * f1 + cl[t + 512] * f2;
    }
#pragma unroll
    for (int c = 0; c < NCLS; ++c) {
        float v = dots[c];
#pragma unroll
        for (int off = 32; off >= 1; off >>= 1) v += __shfl_xor(v, off, 64);
        if (lane == 0) wdot[wv][c] = v;
    }
    __syncthreads();

    if (t < NCLS) {
        float tot  = wsum[0] + wsum[1] + wsum[2] + wsum[3];
        float invn = 1.0f / sqrtf(tot);
        float dot  = wdot[0][t] + wdot[1][t] + wdot[2][t] + wdot[3][t];
        float sim  = dot * invn;
        int   mv   = mask[(size_t)(b * NCLS + t) * NPATCH + n];
        cpart[t]   = (mv != 0) ? expf(sim * 2.0f) : 0.0f;
    }
    __syncthreads();
    if (t == 0) {
        float s = 0.f;
#pragma unroll
        for (int c = 0; c < NCLS; ++c) s += cpart[c];
        partial[p] = s;
    }
}

__global__ __launch_bounds__(256) void k_reduce(const float* __restrict__ partial,
                                                float* __restrict__ out) {
    int t = threadIdx.x;
    float s = 0.f;
    for (int i = t; i < NP; i += 256) s += partial[i];
#pragma unroll
    for (int off = 32; off >= 1; off >>= 1) s += __shfl_xor(s, off, 64);
    __shared__ float ws[4];
    if ((t & 63) == 0) ws[t >> 6] = s;
    __syncthreads();
    if (t == 0) out[0] = -logf(ws[0] + ws[1] + ws[2] + ws[3]);
}

// ---------------------------------------------------------------------------
extern "C" void kernel_launch(void* const* d_in, const int* in_sizes, int n_in,
                              void* d_out, int out_size, void* d_ws, size_t ws_size,
                              hipStream_t stream) {
    const float* x      = (const float*)d_in[0];
    const int*   mask   = (const int*)d_in[1];
    const float* conv_w = (const float*)d_in[2];
    const float* conv_b = (const float*)d_in[3];
    const float* latent = (const float*)d_in[4];
    float* out = (float*)d_out;

    // workspace layout (bytes)
    const size_t xbf_bytes  = (size_t)B_ * CIN * HH * WW * 2;  // 33,554,432
    const size_t wb_bytes   = (size_t)HID * KDIM * 2;          // 12,582,912
    const size_t pslice     = (size_t)NP * HID * 2;            // 3,145,728 (bf16)
    const size_t small_need = (size_t)NCLS * HID * 4 + NP * 4 + 256;

    char* base = (char*)d_ws;
    ushort* xbf  = (ushort*)base;
    ushort* wb   = (ushort*)(base + xbf_bytes);
    ushort* pbuf = (ushort*)(base + xbf_bytes + wb_bytes);

    int splitk = 1;
    const size_t fixed = xbf_bytes + wb_bytes + small_need;
    if (ws_size >= fixed + 8 * pslice)      splitk = 8;
    else if (ws_size >= fixed + 4 * pslice) splitk = 4;
    else if (ws_size >= fixed + 2 * pslice) splitk = 2;

    float* classlat = (float*)(base + xbf_bytes + wb_bytes + (size_t)splitk * pslice);
    float* partial  = classlat + NCLS * HID;

    k_prep<<<NB_CL + NB_W4 + NB_XC, 256, 0, stream>>>(conv_w, x, latent,
                                                      wb, xbf, classlat);

    dim3 g(NP / 256, HID / 128, splitk);
    switch (splitk) {
        case 8: k_gemm<8><<<g, 512, 0, stream>>>(xbf, wb, pbuf); break;
        case 4: k_gemm<4><<<g, 512, 0, stream>>>(xbf, wb, pbuf); break;
        case 2: k_gemm<2><<<g, 512, 0, stream>>>(xbf, wb, pbuf); break;
        default: k_gemm<1><<<g, 512, 0, stream>>>(xbf, wb, pbuf); break;
    }

    switch (splitk) {
        case 8: k_final<8><<<NP, 256, 0, stream>>>(pbuf, conv_b, classlat, mask, partial); break;
        case 4: k_final<4><<<NP, 256, 0, stream>>>(pbuf, conv_b, classlat, mask, partial); break;
        case 2: k_final<2><<<NP, 256, 0, stream>>>(pbuf, conv_b, classlat, mask, partial); break;
        default: k_final<1><<<NP, 256, 0, stream>>>(pbuf, conv_b, classlat, mask, partial); break;
    }
    k_reduce<<<1, 256, 0, stream>>>(partial, out);
}